// Round 12
// baseline (109.659 us; speedup 1.0000x reference)
//
#include <hip/hip_runtime.h>
#include <stdint.h>

typedef unsigned short u16;
typedef unsigned int u32;
typedef __attribute__((ext_vector_type(8))) short short8;
typedef __attribute__((ext_vector_type(4))) float f32x4;

#define B_    8
#define N_    4096
#define DIM_  256
#define HD_   2048
#define NQKV_ 4096

__device__ __forceinline__ float bf2f(u16 u) {
  union { u32 u; float f; } v; v.u = ((u32)u) << 16; return v.f;
}
__device__ __forceinline__ u16 f2bf(float f) {
  union { float f; u32 u; } v; v.f = f;
  u32 r = v.u + 0x7fffu + ((v.u >> 16) & 1u);
  return (u16)(r >> 16);
}
__device__ __forceinline__ float ldin(const void* p, size_t i, int isbf) {
  return isbf ? bf2f(((const u16*)p)[i]) : ((const float*)p)[i];
}
__device__ __forceinline__ void load16_to_lds(const u16* gsrc, u16* ldst) {
  auto gp = (const __attribute__((address_space(1))) void*)(uintptr_t)gsrc;
  auto lp = (__attribute__((address_space(3))) void*)(uintptr_t)ldst;
  __builtin_amdgcn_global_load_lds(gp, lp, 16, 0, 0);
}
__device__ __forceinline__ int probe_isbf(const void* x) {
  u32 w = ((const u32*)x)[threadIdx.x & 63];
  int e = (int)((w >> 7) & 0xff);
  unsigned long long m = __ballot(e >= 118 && e <= 130);
  return __popcll(m) >= 32;
}

// ---- merged: cvtsum (x->bf16 + colsum parts) | wv | tr_pt | Psum | qb | pbv | Lsum ----
__global__ void cvtprep_kernel(const void* __restrict__ x, const void* __restrict__ qkv_w,
                               const void* __restrict__ proj_w, const void* __restrict__ qkv_b,
                               const void* __restrict__ proj_b, const void* __restrict__ lunchbox,
                               u16* __restrict__ xb, float* __restrict__ part,
                               u16* __restrict__ wv, u16* __restrict__ pt,
                               float* __restrict__ Psum, float* __restrict__ qb,
                               float* __restrict__ pbv, float* __restrict__ Lsum) {
  int isbf = probe_isbf(x);
  int bid = blockIdx.x, t = threadIdx.x;
  __shared__ float sm[8][256];
  __shared__ float tile[32][33];
  if (bid < 1024) {
    int b = bid >> 7, ch = bid & 127;
    int c8 = (t & 31) * 8, rg = t >> 5;
    float s[8] = {0.f, 0.f, 0.f, 0.f, 0.f, 0.f, 0.f, 0.f};
#pragma unroll
    for (int i = 0; i < 4; ++i) {
      int row = rg * 4 + i;
      size_t off = ((size_t)b * N_ + (size_t)ch * 32 + row) * DIM_ + c8;
      if (isbf) {
        short8 v = *(const short8*)((const u16*)x + off);
        *(short8*)(xb + off) = v;
#pragma unroll
        for (int j = 0; j < 8; ++j) s[j] += bf2f((u16)v[j]);
      } else {
        f32x4 a = *(const f32x4*)((const float*)x + off);
        f32x4 bb = *(const f32x4*)((const float*)x + off + 4);
        short8 o;
        o[0] = (short)f2bf(a[0]); o[1] = (short)f2bf(a[1]);
        o[2] = (short)f2bf(a[2]); o[3] = (short)f2bf(a[3]);
        o[4] = (short)f2bf(bb[0]); o[5] = (short)f2bf(bb[1]);
        o[6] = (short)f2bf(bb[2]); o[7] = (short)f2bf(bb[3]);
        *(short8*)(xb + off) = o;
        s[0] += a[0]; s[1] += a[1]; s[2] += a[2]; s[3] += a[3];
        s[4] += bb[0]; s[5] += bb[1]; s[6] += bb[2]; s[7] += bb[3];
      }
    }
#pragma unroll
    for (int j = 0; j < 8; ++j) sm[rg][c8 + j] = s[j];
    __syncthreads();
    float tot = 0.f;
#pragma unroll
    for (int r = 0; r < 8; ++r) tot += sm[r][t];
    part[(b * 128 + ch) * DIM_ + t] = tot;
  } else if (bid < 1280) {
    size_t i = ((size_t)(bid - 1024) * 256 + t) * 8;
    int k = (int)(i >> 11), e = (int)(i & 2047);
    size_t src = (size_t)k * NQKV_ + HD_ + e;
    short8 o;
#pragma unroll
    for (int j = 0; j < 8; ++j) o[j] = (short)f2bf(ldin(qkv_w, src + j, isbf));
    *(short8*)&wv[i] = o;
  } else if (bid < 1792) {
    int bid2 = bid - 1280;
    int c0 = (bid2 & 7) * 32, e0 = (bid2 >> 3) * 32;
    int tx = t & 31, ty = t >> 5;
    for (int i = ty; i < 32; i += 8)
      tile[i][tx] = ldin(proj_w, (size_t)(e0 + i) * 256 + c0 + tx, isbf);
    __syncthreads();
    for (int i = ty; i < 32; i += 8)
      pt[(size_t)(c0 + i) * HD_ + e0 + tx] = f2bf(tile[tx][i]);
  } else if (bid < 2048) {
    int d = bid - 1792;
    float s = 0.f;
    for (int jj = 0; jj < 8; ++jj) s += ldin(proj_w, (size_t)(jj * 256 + d) * 256 + t, isbf);
    Psum[d * 256 + t] = s;
  } else if (bid < 2064) {
    int i = (bid - 2048) * 256 + t;
    qb[i] = ldin(qkv_b, i, isbf);
  } else if (bid == 2064) {
    pbv[t] = ldin(proj_b, t, isbf);
  } else {
    float s = 0.f;
    for (int r = 0; r < 32; ++r) s += ldin(lunchbox, (size_t)t * 32 + r, isbf);
    Lsum[t] = s;
  }
}

// ---- gpart: per-block xsum slice reduce + partial dot ----
__global__ void gpart_kernel(const void* __restrict__ xraw, const void* __restrict__ qkv_w,
                             const float* __restrict__ part, float* __restrict__ gpart) {
  int isbf = probe_isbf(xraw);
  int bid = blockIdx.x, t = threadIdx.x;
  int kc = bid & 3, hc = (bid >> 2) & 7, b = bid >> 5;
  __shared__ float red[4][64];
  __shared__ float xs[64];
  {
    int col = t & 63, q = t >> 6;
    float s = 0.f;
    for (int i = 0; i < 32; ++i)
      s += part[(b * 128 + q * 32 + i) * 256 + kc * 64 + col];
    red[q][col] = s;
  }
  __syncthreads();
  if (t < 64) xs[t] = red[0][t] + red[1][t] + red[2][t] + red[3][t];
  __syncthreads();
  int hd = hc * 256 + t;
  float s = 0.f;
#pragma unroll 8
  for (int i = 0; i < 64; ++i)
    s += xs[i] * ldin(qkv_w, (size_t)(kc * 64 + i) * NQKV_ + hd, isbf);
  gpart[kc * 16384 + b * HD_ + hd] = s;
}

// ---- gfin: g[b][hd] + rcpart[ds][bh][c] ----
__global__ void gfin_kernel(const float* __restrict__ gpart, const float* __restrict__ qb,
                            const float* __restrict__ Lsum, const float* __restrict__ Psum,
                            float* __restrict__ g, float* __restrict__ rcpart) {
  int bid = blockIdx.x, t = threadIdx.x;
  int ds = bid & 3, bh = bid >> 2;
  int b = bh >> 3, h = bh & 7;
  __shared__ float us[64];
  if (t < 64) {
    int d = ds * 64 + t, hd = h * 256 + d;
    float sum = gpart[b * HD_ + hd] + gpart[16384 + b * HD_ + hd] +
                gpart[32768 + b * HD_ + hd] + gpart[49152 + b * HD_ + hd];
    float gg = 0.0625f * (sum + 4096.0f * qb[hd]) * Lsum[d];
    g[b * HD_ + hd] = gg;
    us[t] = gg * qb[HD_ + hd];
  }
  __syncthreads();
  float r = 0.f;
#pragma unroll 8
  for (int i = 0; i < 64; ++i)
    r += us[i] * Psum[(ds * 64 + i) * 256 + t];
  rcpart[ds * 16384 + bh * 256 + t] = r;
}

// ---- wg[b][k][e] = bf16( wv[k][e] * g[b][e] ) ----
__global__ void wgscale_kernel(const u16* __restrict__ wv, const float* __restrict__ g,
                               u16* __restrict__ wg) {
  int b = blockIdx.x >> 8;
  size_t i = ((size_t)(blockIdx.x & 255) * 256 + threadIdx.x) * 8;
  int e = (int)(i & 2047);
  short8 w8 = *(const short8*)&wv[i];
  f32x4 g0 = *(const f32x4*)&g[b * HD_ + e];
  f32x4 g1 = *(const f32x4*)&g[b * HD_ + e + 4];
  short8 o;
  o[0] = (short)f2bf(bf2f((u16)w8[0]) * g0[0]);
  o[1] = (short)f2bf(bf2f((u16)w8[1]) * g0[1]);
  o[2] = (short)f2bf(bf2f((u16)w8[2]) * g0[2]);
  o[3] = (short)f2bf(bf2f((u16)w8[3]) * g0[3]);
  o[4] = (short)f2bf(bf2f((u16)w8[4]) * g1[0]);
  o[5] = (short)f2bf(bf2f((u16)w8[5]) * g1[1]);
  o[6] = (short)f2bf(bf2f((u16)w8[6]) * g1[2]);
  o[7] = (short)f2bf(bf2f((u16)w8[7]) * g1[3]);
  *(short8*)&wg[(size_t)b * 524288 + i] = o;
}

// ======== shared counted-vmcnt pipeline pieces (depth-4, never-drain) ========
#define PIPE_STAGE(Abase_, Bbase_, kt_, dst_)                                       \
  {                                                                                 \
    int kcol = (kt_) * 32;                                                          \
    _Pragma("unroll") for (int it = 0; it < 2; ++it) {                              \
      int idx = it * 256 + t, row = idx >> 2, slot = idx & 3;                       \
      int sc = kcol + ((slot ^ ((row >> 1) & 3)) * 8);                              \
      load16_to_lds((Abase_) + (size_t)row * HD_ + sc, (u16*)(dst_) + idx * 8);     \
      load16_to_lds((Bbase_) + (size_t)row * HD_ + sc,                              \
                    (u16*)((char*)(dst_) + 8192) + idx * 8);                        \
    }                                                                               \
  }
#define PIPE_COMP(buf_)                                                             \
  {                                                                                 \
    const u16* lA = (const u16*)(buf_);                                             \
    const u16* lB = (const u16*)((char*)(buf_) + 8192);                             \
    short8 af[4], bfr[4];                                                           \
    _Pragma("unroll") for (int mi = 0; mi < 4; ++mi) {                              \
      int row = wr * 64 + mi * 16 + (lane & 15);                                    \
      af[mi] = *(const short8*)&lA[row * 32 + (((lane >> 4) ^ ((row >> 1) & 3)) * 8)]; \
    }                                                                               \
    _Pragma("unroll") for (int ni = 0; ni < 4; ++ni) {                              \
      int row = wc * 64 + ni * 16 + (lane & 15);                                    \
      bfr[ni] = *(const short8*)&lB[row * 32 + (((lane >> 4) ^ ((row >> 1) & 3)) * 8)]; \
    }                                                                               \
    _Pragma("unroll") for (int mi = 0; mi < 4; ++mi)                                \
      _Pragma("unroll") for (int ni = 0; ni < 4; ++ni)                              \
        acc[mi][ni] = __builtin_amdgcn_mfma_f32_16x16x32_bf16(af[mi], bfr[ni],      \
                                                              acc[mi][ni], 0, 0, 0); \
  }
#define PIPE_ITER(Abase_, Bbase_, kt_, nb_, KI_)                                    \
  {                                                                                 \
    if ((kt_) < (KI_)-2) PIPE_STAGE(Abase_, Bbase_, (kt_) + 2, smem + (nb_) * 16384); \
    if ((kt_) < (KI_)-2)       { asm volatile("s_waitcnt vmcnt(8)" ::: "memory"); } \
    else if ((kt_) == (KI_)-2) { asm volatile("s_waitcnt vmcnt(4)" ::: "memory"); } \
    else                       { asm volatile("s_waitcnt vmcnt(0)" ::: "memory"); } \
    __builtin_amdgcn_s_barrier();                                                   \
    __builtin_amdgcn_sched_barrier(0);                                              \
    PIPE_COMP(smem + ((kt_) & 3) * 16384);                                          \
  }

// ---- stage 1 v4: Mt tile (b,h,jj,quad) 128x128, K=256, depth-4 pipeline ----
__global__ __launch_bounds__(256, 2) void stage1_kernel(
    const u16* __restrict__ pt, const u16* __restrict__ wg,
    u16* __restrict__ Mt, int b0, int nblk) {
  __shared__ alignas(16) char smem[65536];  // 4 bufs x (A 8K + B 8K); eps aliases buf0
  float* eps = (float*)smem;

  int bid = blockIdx.x;
  int sid = (bid & 7) * (nblk >> 3) + (bid >> 3);
  int cq = sid & 1, kq = (sid >> 1) & 1, jj = (sid >> 2) & 7;
  int h = (sid >> 5) & 7, bb = sid >> 8;
  int b = b0 + bb;
  int c0 = cq * 128, k0 = kq * 128;
  const int panel = bb * 8 + h;
  const u16* Abase = pt + (size_t)c0 * HD_ + jj * 256;
  const u16* Bbase = wg + (size_t)b * 524288 + (size_t)k0 * HD_ + h * 256;

  const int t = threadIdx.x, lane = t & 63, wave = t >> 6;
  const int wr = wave >> 1, wc = wave & 1;

  f32x4 acc[4][4] = {};

  PIPE_STAGE(Abase, Bbase, 0, smem);
  PIPE_STAGE(Abase, Bbase, 1, smem + 16384);
#pragma unroll 1
  for (int u = 0; u < 2; ++u) {
    int k4 = u * 4;
    PIPE_ITER(Abase, Bbase, k4 + 0, 2, 8);
    PIPE_ITER(Abase, Bbase, k4 + 1, 3, 8);
    PIPE_ITER(Abase, Bbase, k4 + 2, 0, 8);
    PIPE_ITER(Abase, Bbase, k4 + 3, 1, 8);
  }

  // single-pass epilogue: 4 slabs [32][128], bf16 store to Mt
  const int rl = t >> 3, cc = (t & 7) * 16;
#pragma unroll
  for (int mi = 0; mi < 4; ++mi) {
    __syncthreads();
#pragma unroll
    for (int ni = 0; ni < 4; ++ni) {
      f32x4 v = acc[mi][ni];
      int re = wr * 16 + (lane >> 4) * 4, ce = wc * 64 + ni * 16 + (lane & 15);
      eps[(re + 0) * 128 + ce] = v[0];
      eps[(re + 1) * 128 + ce] = v[1];
      eps[(re + 2) * 128 + ce] = v[2];
      eps[(re + 3) * 128 + ce] = v[3];
    }
    __syncthreads();
    int rowloc = (rl >> 4) * 64 + mi * 16 + (rl & 15);
    alignas(16) u16 pk[16];
#pragma unroll
    for (int j = 0; j < 16; ++j) pk[j] = f2bf(eps[rl * 128 + cc + j]);
    u16* dst = Mt + (size_t)panel * 524288 + (size_t)(c0 + rowloc) * HD_ + jj * 256 + k0 + cc;
    *(short8*)dst = *(short8*)pk;
    *(short8*)(dst + 8) = *(short8*)(pk + 8);
  }
}

// ---- stage 2 v7: out tile (b,h,rt,ct) 128x128, K=2048, depth-4 pipeline ----
__global__ __launch_bounds__(256, 2) void stage2_kernel(
    const void* __restrict__ xraw, const u16* __restrict__ xb, const u16* __restrict__ Mt,
    const float* __restrict__ rcpart, const float* __restrict__ pbv,
    void* __restrict__ outv, int b0, int nblk) {
  __shared__ alignas(16) char smem[65536];  // 4 bufs x (A 8K + B 8K); eps aliases buf0
  float* eps = (float*)smem;

  int bid = blockIdx.x;
  int sid = (bid & 7) * (nblk >> 3) + (bid >> 3);
  int ct = sid & 1, rt = (sid >> 1) & 3, h = (sid >> 3) & 7, bb = sid >> 6;
  int b = b0 + bb;
  int nn0 = rt * 128, c0 = ct * 128;
  const int panel = bb * 8 + h;
  const u16* Abase = xb + (size_t)b * 1048576 + (size_t)nn0 * HD_;
  const u16* Bbase = Mt + (size_t)panel * 524288 + (size_t)c0 * HD_;

  const int t = threadIdx.x, lane = t & 63, wave = t >> 6;
  const int wr = wave >> 1, wc = wave & 1;

  f32x4 acc[4][4] = {};

  PIPE_STAGE(Abase, Bbase, 0, smem);
  PIPE_STAGE(Abase, Bbase, 1, smem + 16384);
#pragma unroll 1
  for (int u = 0; u < 16; ++u) {
    int k4 = u * 4;
    PIPE_ITER(Abase, Bbase, k4 + 0, 2, 64);
    PIPE_ITER(Abase, Bbase, k4 + 1, 3, 64);
    PIPE_ITER(Abase, Bbase, k4 + 2, 0, 64);
    PIPE_ITER(Abase, Bbase, k4 + 3, 1, 64);
  }

  // epilogue: rc finalization + 4 slabs [32][128]
  int isbf = probe_isbf(xraw);
  const int rl = t >> 3, cc = (t & 7) * 16;
  float rc[16];
  {
    const float* rp = rcpart + (size_t)(b * 8 + h) * 256 + c0 + cc;
    const float* pb = pbv + c0 + cc;
#pragma unroll
    for (int j = 0; j < 16; ++j)
      rc[j] = rp[j] + rp[16384 + j] + rp[32768 + j] + rp[49152 + j] + pb[j];
  }
#pragma unroll
  for (int mi = 0; mi < 4; ++mi) {
    __syncthreads();
#pragma unroll
    for (int ni = 0; ni < 4; ++ni) {
      f32x4 v = acc[mi][ni];
      int re = wr * 16 + (lane >> 4) * 4, ce = wc * 64 + ni * 16 + (lane & 15);
      eps[(re + 0) * 128 + ce] = v[0];
      eps[(re + 1) * 128 + ce] = v[1];
      eps[(re + 2) * 128 + ce] = v[2];
      eps[(re + 3) * 128 + ce] = v[3];
    }
    __syncthreads();
    int grow = b * N_ + h * 512 + nn0 + (rl >> 4) * 64 + mi * 16 + (rl & 15);
    if (isbf) {
      alignas(16) u16 pk[16];
#pragma unroll
      for (int j = 0; j < 16; ++j) pk[j] = f2bf(eps[rl * 128 + cc + j] + rc[j]);
      u16* op = (u16*)outv + (size_t)grow * 256 + c0 + cc;
      *(short8*)op = *(short8*)pk;
      *(short8*)(op + 8) = *(short8*)(pk + 8);
    } else {
      float* op = (float*)outv + (size_t)grow * 256 + c0 + cc;
#pragma unroll
      for (int chv = 0; chv < 4; ++chv) {
        f32x4 o_;
        o_[0] = eps[rl * 128 + cc + chv * 4 + 0] + rc[chv * 4 + 0];
        o_[1] = eps[rl * 128 + cc + chv * 4 + 1] + rc[chv * 4 + 1];
        o_[2] = eps[rl * 128 + cc + chv * 4 + 2] + rc[chv * 4 + 2];
        o_[3] = eps[rl * 128 + cc + chv * 4 + 3] + rc[chv * 4 + 3];
        ((f32x4*)op)[chv] = o_;
      }
    }
  }
}

extern "C" void kernel_launch(void* const* d_in, const int* in_sizes, int n_in,
                              void* d_out, int out_size, void* d_ws, size_t ws_size,
                              hipStream_t stream) {
  const void* x        = d_in[0];
  const void* qkv_w    = d_in[1];
  const void* qkv_b    = d_in[2];
  const void* lunchbox = d_in[3];
  const void* proj_w   = d_in[4];
  const void* proj_b   = d_in[5];
  char* ws = (char*)d_ws;

  u16*   xbuf   = (u16*)(ws + 0);            // 16 MiB
  u16*   wv     = (u16*)(ws + 16777216);     // 1 MiB
  u16*   pt     = (u16*)(ws + 17825792);     // 1 MiB
  float* part   = (float*)(ws + 18874368);   // 1 MiB
  float* g      = (float*)(ws + 19922944);   // 64 KiB
  float* gpart  = (float*)(ws + 19988480);   // 256 KiB
  float* rcpart = (float*)(ws + 20250624);   // 256 KiB
  float* Psum   = (float*)(ws + 20512768);   // 256 KiB
  float* qb     = (float*)(ws + 20774912);   // 16 KiB
  float* pbv    = (float*)(ws + 20791296);   // 1 KiB
  float* Lsum   = (float*)(ws + 20792320);   // 1 KiB
  u16*   wg     = (u16*)(ws + 20971520);     // 8 MiB
  u16*   Mt     = (u16*)(ws + 29360128);     // up to 64 MiB

  cvtprep_kernel<<<2066, 256, 0, stream>>>(x, qkv_w, proj_w, qkv_b, proj_b, lunchbox,
                                           xbuf, part, wv, pt, Psum, qb, pbv, Lsum);
  gpart_kernel<<<256, 256, 0, stream>>>(x, qkv_w, part, gpart);
  gfin_kernel<<<256, 256, 0, stream>>>(gpart, qb, Lsum, Psum, g, rcpart);
  wgscale_kernel<<<2048, 256, 0, stream>>>(wv, g, wg);

  size_t mt_off = 29360128;
  int gb = 8;
  while (gb > 1 && mt_off + (size_t)gb * 8388608 > ws_size) gb >>= 1;
  for (int b0 = 0; b0 < 8; b0 += gb) {
    stage1_kernel<<<gb * 256, 256, 0, stream>>>(pt, wg, Mt, b0, gb * 256);
    stage2_kernel<<<gb * 64, 256, 0, stream>>>(x, xbuf, Mt, rcpart, pbv, d_out, b0, gb * 64);
  }
}

// Round 13
// 97.485 us; speedup vs baseline: 1.1249x; 1.1249x over previous
//
#include <hip/hip_runtime.h>
#include <stdint.h>

typedef unsigned short u16;
typedef unsigned int u32;
typedef __attribute__((ext_vector_type(8))) short short8;
typedef __attribute__((ext_vector_type(4))) float f32x4;

#define B_    8
#define N_    4096
#define DIM_  256
#define HD_   2048
#define NQKV_ 4096

__device__ __forceinline__ float bf2f(u16 u) {
  union { u32 u; float f; } v; v.u = ((u32)u) << 16; return v.f;
}
__device__ __forceinline__ u16 f2bf(float f) {
  union { float f; u32 u; } v; v.f = f;
  u32 r = v.u + 0x7fffu + ((v.u >> 16) & 1u);
  return (u16)(r >> 16);
}
__device__ __forceinline__ float ldin(const void* p, size_t i, int isbf) {
  return isbf ? bf2f(((const u16*)p)[i]) : ((const float*)p)[i];
}
__device__ __forceinline__ void load16_to_lds(const u16* gsrc, u16* ldst) {
  auto gp = (const __attribute__((address_space(1))) void*)(uintptr_t)gsrc;
  auto lp = (__attribute__((address_space(3))) void*)(uintptr_t)ldst;
  __builtin_amdgcn_global_load_lds(gp, lp, 16, 0, 0);
}
__device__ __forceinline__ int probe_isbf(const void* x) {
  u32 w = ((const u32*)x)[threadIdx.x & 63];
  int e = (int)((w >> 7) & 0xff);
  unsigned long long m = __ballot(e >= 118 && e <= 130);
  return __popcll(m) >= 32;
}

// ---- merged: cvtsum (x->bf16 + colsum parts) | wv | tr_pt | Psum | qb | pbv | Lsum ----
__global__ void cvtprep_kernel(const void* __restrict__ x, const void* __restrict__ qkv_w,
                               const void* __restrict__ proj_w, const void* __restrict__ qkv_b,
                               const void* __restrict__ proj_b, const void* __restrict__ lunchbox,
                               u16* __restrict__ xb, float* __restrict__ part,
                               u16* __restrict__ wv, u16* __restrict__ pt,
                               float* __restrict__ Psum, float* __restrict__ qb,
                               float* __restrict__ pbv, float* __restrict__ Lsum) {
  int isbf = probe_isbf(x);
  int bid = blockIdx.x, t = threadIdx.x;
  __shared__ float sm[8][256];
  __shared__ float tile[32][33];
  if (bid < 1024) {
    int b = bid >> 7, ch = bid & 127;
    int c8 = (t & 31) * 8, rg = t >> 5;
    float s[8] = {0.f, 0.f, 0.f, 0.f, 0.f, 0.f, 0.f, 0.f};
#pragma unroll
    for (int i = 0; i < 4; ++i) {
      int row = rg * 4 + i;
      size_t off = ((size_t)b * N_ + (size_t)ch * 32 + row) * DIM_ + c8;
      if (isbf) {
        short8 v = *(const short8*)((const u16*)x + off);
        *(short8*)(xb + off) = v;
#pragma unroll
        for (int j = 0; j < 8; ++j) s[j] += bf2f((u16)v[j]);
      } else {
        f32x4 a = *(const f32x4*)((const float*)x + off);
        f32x4 bb = *(const f32x4*)((const float*)x + off + 4);
        short8 o;
        o[0] = (short)f2bf(a[0]); o[1] = (short)f2bf(a[1]);
        o[2] = (short)f2bf(a[2]); o[3] = (short)f2bf(a[3]);
        o[4] = (short)f2bf(bb[0]); o[5] = (short)f2bf(bb[1]);
        o[6] = (short)f2bf(bb[2]); o[7] = (short)f2bf(bb[3]);
        *(short8*)(xb + off) = o;
        s[0] += a[0]; s[1] += a[1]; s[2] += a[2]; s[3] += a[3];
        s[4] += bb[0]; s[5] += bb[1]; s[6] += bb[2]; s[7] += bb[3];
      }
    }
#pragma unroll
    for (int j = 0; j < 8; ++j) sm[rg][c8 + j] = s[j];
    __syncthreads();
    float tot = 0.f;
#pragma unroll
    for (int r = 0; r < 8; ++r) tot += sm[r][t];
    part[(b * 128 + ch) * DIM_ + t] = tot;
  } else if (bid < 1280) {
    size_t i = ((size_t)(bid - 1024) * 256 + t) * 8;
    int k = (int)(i >> 11), e = (int)(i & 2047);
    size_t src = (size_t)k * NQKV_ + HD_ + e;
    short8 o;
#pragma unroll
    for (int j = 0; j < 8; ++j) o[j] = (short)f2bf(ldin(qkv_w, src + j, isbf));
    *(short8*)&wv[i] = o;
  } else if (bid < 1792) {
    int bid2 = bid - 1280;
    int c0 = (bid2 & 7) * 32, e0 = (bid2 >> 3) * 32;
    int tx = t & 31, ty = t >> 5;
    for (int i = ty; i < 32; i += 8)
      tile[i][tx] = ldin(proj_w, (size_t)(e0 + i) * 256 + c0 + tx, isbf);
    __syncthreads();
    for (int i = ty; i < 32; i += 8)
      pt[(size_t)(c0 + i) * HD_ + e0 + tx] = f2bf(tile[tx][i]);
  } else if (bid < 2048) {
    int d = bid - 1792;
    float s = 0.f;
    for (int jj = 0; jj < 8; ++jj) s += ldin(proj_w, (size_t)(jj * 256 + d) * 256 + t, isbf);
    Psum[d * 256 + t] = s;
  } else if (bid < 2064) {
    int i = (bid - 2048) * 256 + t;
    qb[i] = ldin(qkv_b, i, isbf);
  } else if (bid == 2064) {
    pbv[t] = ldin(proj_b, t, isbf);
  } else {
    float s = 0.f;
    for (int r = 0; r < 32; ++r) s += ldin(lunchbox, (size_t)t * 32 + r, isbf);
    Lsum[t] = s;
  }
}

// ---- gpart: per-block xsum slice reduce + partial dot ----
__global__ void gpart_kernel(const void* __restrict__ xraw, const void* __restrict__ qkv_w,
                             const float* __restrict__ part, float* __restrict__ gpart) {
  int isbf = probe_isbf(xraw);
  int bid = blockIdx.x, t = threadIdx.x;
  int kc = bid & 3, hc = (bid >> 2) & 7, b = bid >> 5;
  __shared__ float red[4][64];
  __shared__ float xs[64];
  {
    int col = t & 63, q = t >> 6;
    float s = 0.f;
    for (int i = 0; i < 32; ++i)
      s += part[(b * 128 + q * 32 + i) * 256 + kc * 64 + col];
    red[q][col] = s;
  }
  __syncthreads();
  if (t < 64) xs[t] = red[0][t] + red[1][t] + red[2][t] + red[3][t];
  __syncthreads();
  int hd = hc * 256 + t;
  float s = 0.f;
#pragma unroll 8
  for (int i = 0; i < 64; ++i)
    s += xs[i] * ldin(qkv_w, (size_t)(kc * 64 + i) * NQKV_ + hd, isbf);
  gpart[kc * 16384 + b * HD_ + hd] = s;
}

// ---- gfin: g[b][hd] + rcpart[ds][bh][c] ----
__global__ void gfin_kernel(const float* __restrict__ gpart, const float* __restrict__ qb,
                            const float* __restrict__ Lsum, const float* __restrict__ Psum,
                            float* __restrict__ g, float* __restrict__ rcpart) {
  int bid = blockIdx.x, t = threadIdx.x;
  int ds = bid & 3, bh = bid >> 2;
  int b = bh >> 3, h = bh & 7;
  __shared__ float us[64];
  if (t < 64) {
    int d = ds * 64 + t, hd = h * 256 + d;
    float sum = gpart[b * HD_ + hd] + gpart[16384 + b * HD_ + hd] +
                gpart[32768 + b * HD_ + hd] + gpart[49152 + b * HD_ + hd];
    float gg = 0.0625f * (sum + 4096.0f * qb[hd]) * Lsum[d];
    g[b * HD_ + hd] = gg;
    us[t] = gg * qb[HD_ + hd];
  }
  __syncthreads();
  float r = 0.f;
#pragma unroll 8
  for (int i = 0; i < 64; ++i)
    r += us[i] * Psum[(ds * 64 + i) * 256 + t];
  rcpart[ds * 16384 + bh * 256 + t] = r;
}

// ---- stage 1 (round-10 proven): W'(g-scaled, swizzled) in LDS, reused across 4 jj-tiles ----
__global__ __launch_bounds__(256, 2) void stage1_kernel(
    const u16* __restrict__ pt, const u16* __restrict__ wv,
    const float* __restrict__ g, u16* __restrict__ Mt, int b0) {
  __shared__ alignas(16) char smem[81920];
  u16* Wp = (u16*)smem;
  char* Adb = smem + 65536;
  float* eps = (float*)(smem + 65536);

  int bid = blockIdx.x;
  int c0i = bid & 1, jh = (bid >> 1) & 1, k0i = (bid >> 2) & 1;
  int h = (bid >> 3) & 7, bb = bid >> 6;
  int b = b0 + bb;
  int c0 = c0i * 128, k0 = k0i * 128;
  const int t = threadIdx.x, lane = t & 63, wave = t >> 6;
  const int wr = wave >> 1, wc = wave & 1;
  const int panel = bb * 8 + h;

  {
    const u16* wsrc = wv + (size_t)k0 * HD_ + h * 256;
    const float* gp = g + b * HD_ + h * 256;
#pragma unroll
    for (int it = 0; it < 16; ++it) {
      int idx = it * 256 + t;
      int row = idx >> 5, chunk = idx & 31;
      short8 w8 = *(const short8*)&wsrc[(size_t)row * HD_ + chunk * 8];
      f32x4 g0 = *(const f32x4*)&gp[chunk * 8];
      f32x4 g1 = *(const f32x4*)&gp[chunk * 8 + 4];
      short8 o;
      o[0] = (short)f2bf(bf2f((u16)w8[0]) * g0[0]);
      o[1] = (short)f2bf(bf2f((u16)w8[1]) * g0[1]);
      o[2] = (short)f2bf(bf2f((u16)w8[2]) * g0[2]);
      o[3] = (short)f2bf(bf2f((u16)w8[3]) * g0[3]);
      o[4] = (short)f2bf(bf2f((u16)w8[4]) * g1[0]);
      o[5] = (short)f2bf(bf2f((u16)w8[5]) * g1[1]);
      o[6] = (short)f2bf(bf2f((u16)w8[6]) * g1[2]);
      o[7] = (short)f2bf(bf2f((u16)w8[7]) * g1[3]);
      *(short8*)&Wp[row * 256 + ((chunk ^ (row & 7)) * 8)] = o;
    }
  }
  __syncthreads();

#define S1_STAGE(jj, ks, bi)                                                          \
  {                                                                                   \
    _Pragma("unroll") for (int it = 0; it < 2; ++it) {                                \
      int idx = it * 256 + t, row = idx >> 2, slot = idx & 3;                         \
      load16_to_lds(pt + (size_t)(c0 + row) * HD_ + (jj) * 256 + (ks) * 32 +          \
                        ((slot ^ (row & 3)) * 8),                                     \
                    (u16*)(Adb + (bi) * 8192) + idx * 8);                             \
    }                                                                                 \
  }

  for (int jc = 0; jc < 4; ++jc) {
    int jj = jh * 4 + jc;
    f32x4 acc[4][4] = {};
    S1_STAGE(jj, 0, 0);
    __syncthreads();
    int cur = 0;
    for (int ks = 0; ks < 8; ++ks) {
      if (ks < 7) S1_STAGE(jj, ks + 1, cur ^ 1);
      const u16* lA = (const u16*)(Adb + cur * 8192);
      short8 af[4], bfr[4];
      const int ar = wr * 64 + (lane & 15), bc = wc * 64 + (lane & 15);
#pragma unroll
      for (int mi = 0; mi < 4; ++mi) {
        int row = ar + mi * 16;
        af[mi] = *(const short8*)&lA[row * 32 + (((lane >> 4) ^ (row & 3)) * 8)];
      }
#pragma unroll
      for (int ni = 0; ni < 4; ++ni) {
        int kl = bc + ni * 16;
        int chunk = ks * 4 + (lane >> 4);
        bfr[ni] = *(const short8*)&Wp[kl * 256 + ((chunk ^ (kl & 7)) * 8)];
      }
#pragma unroll
      for (int mi = 0; mi < 4; ++mi)
#pragma unroll
        for (int ni = 0; ni < 4; ++ni)
          acc[mi][ni] = __builtin_amdgcn_mfma_f32_16x16x32_bf16(af[mi], bfr[ni], acc[mi][ni], 0, 0, 0);
      __syncthreads();
      cur ^= 1;
    }
    const int rl = t >> 3, cc = (t & 7) * 16;
#pragma unroll
    for (int mi = 0; mi < 4; ++mi) {
      __syncthreads();
#pragma unroll
      for (int ni = 0; ni < 4; ++ni) {
        f32x4 v = acc[mi][ni];
        int re = wr * 16 + (lane >> 4) * 4, ce = wc * 64 + ni * 16 + (lane & 15);
        eps[(re + 0) * 128 + ce] = v[0];
        eps[(re + 1) * 128 + ce] = v[1];
        eps[(re + 2) * 128 + ce] = v[2];
        eps[(re + 3) * 128 + ce] = v[3];
      }
      __syncthreads();
      int cg = c0 + (rl >> 4) * 64 + mi * 16 + (rl & 15);
      alignas(16) u16 pk[16];
#pragma unroll
      for (int j = 0; j < 16; ++j) pk[j] = f2bf(eps[rl * 128 + cc + j]);
      u16* dst = Mt + (size_t)panel * 524288 + (size_t)cg * HD_ + jj * 256 + k0 + cc;
      *(short8*)dst = *(short8*)pk;
      *(short8*)(dst + 8) = *(short8*)(pk + 8);
    }
    __syncthreads();
  }
}

// ---- stage 2 (round-11 proven v6): split-K 512 thr + (row>>1)&3 swizzle ----
__global__ __launch_bounds__(512, 4) void stage2_kernel(
    const void* __restrict__ xraw, const u16* __restrict__ xb, const u16* __restrict__ Mt,
    const float* __restrict__ rcpart, const float* __restrict__ pbv,
    void* __restrict__ outv, int b0, int nblk) {
  __shared__ alignas(16) char smem[65536];
  float* eps = (float*)smem;

  int bid = blockIdx.x;
  int sid = (bid & 7) * (nblk >> 3) + (bid >> 3);
  int ct = sid & 1, rt = (sid >> 1) & 3, h = (sid >> 3) & 7, bb = sid >> 6;
  int b = b0 + bb;
  int nn0 = rt * 128, c0 = ct * 128;
  const int panel = bb * 8 + h;
  const u16* Abase = xb + (size_t)b * 1048576 + (size_t)nn0 * HD_;
  const u16* Bbase = Mt + (size_t)panel * 524288 + (size_t)c0 * HD_;

  const int t = threadIdx.x;
  const int grp = t >> 8, tt = t & 255;
  const int lane = tt & 63, wave = tt >> 6;
  const int wr = wave >> 1, wc = wave & 1;
  char* aB0 = smem + grp * 32768;
  char* aB1 = aB0 + 16384;

  f32x4 acc[4][4] = {};

#define S2_STAGE(i_, dst_)                                                          \
  {                                                                                 \
    int kcol = ((i_) * 2 + grp) * 32;                                               \
    _Pragma("unroll") for (int it = 0; it < 2; ++it) {                              \
      int idx = it * 256 + tt, row = idx >> 2, slot = idx & 3;                      \
      int sc = kcol + ((slot ^ ((row >> 1) & 3)) * 8);                              \
      load16_to_lds(Abase + (size_t)row * HD_ + sc, (u16*)(dst_) + idx * 8);        \
      load16_to_lds(Bbase + (size_t)row * HD_ + sc,                                 \
                    (u16*)((char*)(dst_) + 8192) + idx * 8);                        \
    }                                                                               \
  }
#define S2_COMP(buf_)                                                               \
  {                                                                                 \
    const u16* lA = (const u16*)(buf_);                                             \
    const u16* lB = (const u16*)((char*)(buf_) + 8192);                             \
    short8 af[4], bfr[4];                                                           \
    _Pragma("unroll") for (int mi = 0; mi < 4; ++mi) {                              \
      int row = wr * 64 + mi * 16 + (lane & 15);                                    \
      af[mi] = *(const short8*)&lA[row * 32 + (((lane >> 4) ^ ((row >> 1) & 3)) * 8)]; \
    }                                                                               \
    _Pragma("unroll") for (int ni = 0; ni < 4; ++ni) {                              \
      int row = wc * 64 + ni * 16 + (lane & 15);                                    \
      bfr[ni] = *(const short8*)&lB[row * 32 + (((lane >> 4) ^ ((row >> 1) & 3)) * 8)]; \
    }                                                                               \
    _Pragma("unroll") for (int mi = 0; mi < 4; ++mi)                                \
      _Pragma("unroll") for (int ni = 0; ni < 4; ++ni)                              \
        acc[mi][ni] = __builtin_amdgcn_mfma_f32_16x16x32_bf16(af[mi], bfr[ni],      \
                                                              acc[mi][ni], 0, 0, 0); \
  }

  S2_STAGE(0, aB0);
  __syncthreads();
#pragma unroll 1
  for (int ii = 0; ii < 16; ++ii) {
    S2_STAGE(ii * 2 + 1, aB1);
    S2_COMP(aB0);
    __syncthreads();
    if (ii < 15) S2_STAGE(ii * 2 + 2, aB0);
    S2_COMP(aB1);
    __syncthreads();
  }

  int isbf = probe_isbf(xraw);
  const int rl = t >> 4, cc = (t & 15) * 8;
  float rc[8];
  {
    const float* rp = rcpart + (size_t)(b * 8 + h) * 256 + c0 + cc;
    const float* pb = pbv + c0 + cc;
#pragma unroll
    for (int j = 0; j < 8; ++j)
      rc[j] = rp[j] + rp[16384 + j] + rp[32768 + j] + rp[49152 + j] + pb[j];
  }
#pragma unroll
  for (int mi = 0; mi < 4; ++mi) {
    __syncthreads();
    if (grp == 0) {
#pragma unroll
      for (int ni = 0; ni < 4; ++ni) {
        f32x4 v = acc[mi][ni];
        int re = wr * 16 + (lane >> 4) * 4, ce = wc * 64 + ni * 16 + (lane & 15);
        eps[(re + 0) * 128 + ce] = v[0];
        eps[(re + 1) * 128 + ce] = v[1];
        eps[(re + 2) * 128 + ce] = v[2];
        eps[(re + 3) * 128 + ce] = v[3];
      }
    }
    __syncthreads();
    if (grp == 1) {
#pragma unroll
      for (int ni = 0; ni < 4; ++ni) {
        f32x4 v = acc[mi][ni];
        int re = wr * 16 + (lane >> 4) * 4, ce = wc * 64 + ni * 16 + (lane & 15);
        eps[(re + 0) * 128 + ce] += v[0];
        eps[(re + 1) * 128 + ce] += v[1];
        eps[(re + 2) * 128 + ce] += v[2];
        eps[(re + 3) * 128 + ce] += v[3];
      }
    }
    __syncthreads();
    int grow = b * N_ + h * 512 + nn0 + (rl >> 4) * 64 + mi * 16 + (rl & 15);
    if (isbf) {
      alignas(16) u16 pk[8];
#pragma unroll
      for (int j = 0; j < 8; ++j) pk[j] = f2bf(eps[rl * 128 + cc + j] + rc[j]);
      *(short8*)((u16*)outv + (size_t)grow * 256 + c0 + cc) = *(short8*)pk;
    } else {
      float* op = (float*)outv + (size_t)grow * 256 + c0 + cc;
      f32x4 o0, o1;
      o0[0] = eps[rl * 128 + cc + 0] + rc[0];
      o0[1] = eps[rl * 128 + cc + 1] + rc[1];
      o0[2] = eps[rl * 128 + cc + 2] + rc[2];
      o0[3] = eps[rl * 128 + cc + 3] + rc[3];
      o1[0] = eps[rl * 128 + cc + 4] + rc[4];
      o1[1] = eps[rl * 128 + cc + 5] + rc[5];
      o1[2] = eps[rl * 128 + cc + 6] + rc[6];
      o1[3] = eps[rl * 128 + cc + 7] + rc[7];
      ((f32x4*)op)[0] = o0;
      ((f32x4*)op)[1] = o1;
    }
  }
}

extern "C" void kernel_launch(void* const* d_in, const int* in_sizes, int n_in,
                              void* d_out, int out_size, void* d_ws, size_t ws_size,
                              hipStream_t stream) {
  const void* x        = d_in[0];
  const void* qkv_w    = d_in[1];
  const void* qkv_b    = d_in[2];
  const void* lunchbox = d_in[3];
  const void* proj_w   = d_in[4];
  const void* proj_b   = d_in[5];
  char* ws = (char*)d_ws;

  u16*   xbuf   = (u16*)(ws + 0);            // 16 MiB
  u16*   wv     = (u16*)(ws + 16777216);     // 1 MiB
  u16*   pt     = (u16*)(ws + 17825792);     // 1 MiB
  float* part   = (float*)(ws + 18874368);   // 1 MiB
  float* g      = (float*)(ws + 19922944);   // 64 KiB
  float* gpart  = (float*)(ws + 19988480);   // 256 KiB
  float* rcpart = (float*)(ws + 20250624);   // 256 KiB
  float* Psum   = (float*)(ws + 20512768);   // 256 KiB
  float* qb     = (float*)(ws + 20774912);   // 16 KiB
  float* pbv    = (float*)(ws + 20791296);   // 1 KiB
  float* Lsum   = (float*)(ws + 20792320);   // 1 KiB
  u16*   Mt     = (u16*)(ws + 20971520);     // up to 64 MiB

  cvtprep_kernel<<<2066, 256, 0, stream>>>(x, qkv_w, proj_w, qkv_b, proj_b, lunchbox,
                                           xbuf, part, wv, pt, Psum, qb, pbv, Lsum);
  gpart_kernel<<<256, 256, 0, stream>>>(x, qkv_w, part, gpart);
  gfin_kernel<<<256, 256, 0, stream>>>(gpart, qb, Lsum, Psum, g, rcpart);

  size_t mt_off = 20971520;
  int gb = 8;
  while (gb > 1 && mt_off + (size_t)gb * 8388608 > ws_size) gb >>= 1;
  for (int b0 = 0; b0 < 8; b0 += gb) {
    stage1_kernel<<<gb * 64, 256, 0, stream>>>(pt, wv, g, Mt, b0);
    stage2_kernel<<<gb * 64, 512, 0, stream>>>(x, xbuf, Mt, rcpart, pbv, d_out, b0, gb * 64);
  }
}